// Round 1
// baseline (1655.400 us; speedup 1.0000x reference)
//
#include <hip/hip_runtime.h>
#include <cstdint>
#include <cstddef>

// Problem constants
constexpr int B_  = 2;
constexpr int T_  = 2048;
constexpr int D_  = 2048;
constexpr int H_  = 8;
constexpr int HD_ = 128;
constexpr int C_  = 1024;   // H*HD
constexpr int BT_ = 64;
constexpr int NT_ = 32;     // T/BT
constexpr int M_  = 4096;   // B*T
constexpr float EPS_RMS = 1.1920929e-07f;

// ---------------------------------------------------------------------------
// Generic f32 GEMM: C[M,N] = A[M,K] @ B[K,N].  128x128 tile, BK=16, 256 thr,
// 8x8 per thread.  All dims assumed divisible (M%128==0, N%128==0, K%16==0).
// ---------------------------------------------------------------------------
constexpr int GT = 128;
constexpr int GK = 16;

__global__ __launch_bounds__(256) void gemm_f32(
    const float* __restrict__ A, const float* __restrict__ Bm, float* __restrict__ Cm,
    int N, int K) {
  __shared__ float As[GK][GT + 4];
  __shared__ float Bs[GK][GT + 4];
  const int tid = threadIdx.x;
  const int bx = blockIdx.x, by = blockIdx.y;
  const int ar = tid >> 1;
  const int ak = (tid & 1) * 8;
  const int tx = tid & 15, ty = tid >> 4;
  const int br0 = tid >> 5, bc = (tid & 31) * 4;
  float acc[8][8];
#pragma unroll
  for (int i = 0; i < 8; ++i)
#pragma unroll
    for (int j = 0; j < 8; ++j) acc[i][j] = 0.f;
  const float* Ab = A + (size_t)by * GT * K;
  const float* Bb = Bm + (size_t)bx * GT;
  for (int k0 = 0; k0 < K; k0 += GK) {
    const float* ap = Ab + (size_t)ar * K + k0 + ak;
    float4 a0 = *(const float4*)(ap);
    float4 a1 = *(const float4*)(ap + 4);
    float4 b0 = *(const float4*)(Bb + (size_t)(k0 + br0) * N + bc);
    float4 b1 = *(const float4*)(Bb + (size_t)(k0 + 8 + br0) * N + bc);
    __syncthreads();
    As[ak + 0][ar] = a0.x; As[ak + 1][ar] = a0.y; As[ak + 2][ar] = a0.z; As[ak + 3][ar] = a0.w;
    As[ak + 4][ar] = a1.x; As[ak + 5][ar] = a1.y; As[ak + 6][ar] = a1.z; As[ak + 7][ar] = a1.w;
    *(float4*)&Bs[br0][bc] = b0;
    *(float4*)&Bs[8 + br0][bc] = b1;
    __syncthreads();
#pragma unroll
    for (int kk = 0; kk < GK; ++kk) {
      float a8[8], b8[8];
      *(float4*)(a8)     = *(const float4*)&As[kk][ty * 4];
      *(float4*)(a8 + 4) = *(const float4*)&As[kk][ty * 4 + 64];
      *(float4*)(b8)     = *(const float4*)&Bs[kk][tx * 4];
      *(float4*)(b8 + 4) = *(const float4*)&Bs[kk][tx * 4 + 64];
#pragma unroll
      for (int i = 0; i < 8; ++i)
#pragma unroll
        for (int j = 0; j < 8; ++j)
          acc[i][j] = fmaf(a8[i], b8[j], acc[i][j]);
    }
  }
#pragma unroll
  for (int i = 0; i < 8; ++i) {
    int row = by * GT + ty * 4 + (i & 3) + ((i >> 2) << 6);
    float4 v0 = make_float4(acc[i][0], acc[i][1], acc[i][2], acc[i][3]);
    float4 v1 = make_float4(acc[i][4], acc[i][5], acc[i][6], acc[i][7]);
    float* cp = Cm + (size_t)row * N + (size_t)bx * GT + tx * 4;
    *(float4*)(cp) = v0;
    *(float4*)(cp + 64) = v1;
  }
}

// Split-K variant: accumulates into C via atomicAdd (C must be pre-zeroed).
__global__ __launch_bounds__(256) void gemm_f32_splitk(
    const float* __restrict__ A, const float* __restrict__ Bm, float* __restrict__ Cm,
    int N, int K, int KS) {
  __shared__ float As[GK][GT + 4];
  __shared__ float Bs[GK][GT + 4];
  const int tid = threadIdx.x;
  const int bx = blockIdx.x, by = blockIdx.y;
  const int kbeg = blockIdx.z * KS;
  const int ar = tid >> 1;
  const int ak = (tid & 1) * 8;
  const int tx = tid & 15, ty = tid >> 4;
  const int br0 = tid >> 5, bc = (tid & 31) * 4;
  float acc[8][8];
#pragma unroll
  for (int i = 0; i < 8; ++i)
#pragma unroll
    for (int j = 0; j < 8; ++j) acc[i][j] = 0.f;
  const float* Ab = A + (size_t)by * GT * K;
  const float* Bb = Bm + (size_t)bx * GT;
  for (int k0 = kbeg; k0 < kbeg + KS; k0 += GK) {
    const float* ap = Ab + (size_t)ar * K + k0 + ak;
    float4 a0 = *(const float4*)(ap);
    float4 a1 = *(const float4*)(ap + 4);
    float4 b0 = *(const float4*)(Bb + (size_t)(k0 + br0) * N + bc);
    float4 b1 = *(const float4*)(Bb + (size_t)(k0 + 8 + br0) * N + bc);
    __syncthreads();
    As[ak + 0][ar] = a0.x; As[ak + 1][ar] = a0.y; As[ak + 2][ar] = a0.z; As[ak + 3][ar] = a0.w;
    As[ak + 4][ar] = a1.x; As[ak + 5][ar] = a1.y; As[ak + 6][ar] = a1.z; As[ak + 7][ar] = a1.w;
    *(float4*)&Bs[br0][bc] = b0;
    *(float4*)&Bs[8 + br0][bc] = b1;
    __syncthreads();
#pragma unroll
    for (int kk = 0; kk < GK; ++kk) {
      float a8[8], b8[8];
      *(float4*)(a8)     = *(const float4*)&As[kk][ty * 4];
      *(float4*)(a8 + 4) = *(const float4*)&As[kk][ty * 4 + 64];
      *(float4*)(b8)     = *(const float4*)&Bs[kk][tx * 4];
      *(float4*)(b8 + 4) = *(const float4*)&Bs[kk][tx * 4 + 64];
#pragma unroll
      for (int i = 0; i < 8; ++i)
#pragma unroll
        for (int j = 0; j < 8; ++j)
          acc[i][j] = fmaf(a8[i], b8[j], acc[i][j]);
    }
  }
#pragma unroll
  for (int i = 0; i < 8; ++i) {
    int row = by * GT + ty * 4 + (i & 3) + ((i >> 2) << 6);
#pragma unroll
    for (int j = 0; j < 8; ++j) {
      int col = bx * GT + tx * 4 + (j & 3) + ((j >> 2) << 6);
      atomicAdd(Cm + (size_t)row * N + col, acc[i][j]);
    }
  }
}

// ---------------------------------------------------------------------------
// Causal depthwise conv (window 4) + bias, then per-(b,t,h) L2 normalize,
// write to (B,H,T,HD) layout.  grid = B*T*H blocks (h fastest), 128 threads.
// ---------------------------------------------------------------------------
__global__ __launch_bounds__(128) void conv_norm_head(
    const float* __restrict__ pre, const float* __restrict__ cw,
    const float* __restrict__ cb, float* __restrict__ outp) {
  int idx = blockIdx.x;
  int h = idx & 7;
  int t = (idx >> 3) & (T_ - 1);
  int b = idx >> 14;
  int d = threadIdx.x;
  int c = h * HD_ + d;
  const float* basep = pre + (size_t)(b * T_ + t) * C_ + c;
  float w0 = cw[c * 4 + 0], w1 = cw[c * 4 + 1], w2 = cw[c * 4 + 2], w3 = cw[c * 4 + 3];
  float acc = cb[c] + w3 * basep[0];
  if (t > 0) acc += w2 * basep[-(ptrdiff_t)C_];
  if (t > 1) acc += w1 * basep[-2 * (ptrdiff_t)C_];
  if (t > 2) acc += w0 * basep[-3 * (ptrdiff_t)C_];
  float ss = acc * acc;
#pragma unroll
  for (int o = 32; o > 0; o >>= 1) ss += __shfl_down(ss, o);
  __shared__ float red[2];
  if ((d & 63) == 0) red[d >> 6] = ss;
  __syncthreads();
  float tot = red[0] + red[1];
  float nrm = fmaxf(sqrtf(tot), 1e-12f);
  outp[(((size_t)b * H_ + h) * T_ + t) * HD_ + d] = acc / nrm;
}

// Same conv but with silu activation (for v), no normalization.
__global__ __launch_bounds__(128) void conv_silu_head(
    const float* __restrict__ pre, const float* __restrict__ cw,
    const float* __restrict__ cb, float* __restrict__ outp) {
  int idx = blockIdx.x;
  int h = idx & 7;
  int t = (idx >> 3) & (T_ - 1);
  int b = idx >> 14;
  int d = threadIdx.x;
  int c = h * HD_ + d;
  const float* basep = pre + (size_t)(b * T_ + t) * C_ + c;
  float w0 = cw[c * 4 + 0], w1 = cw[c * 4 + 1], w2 = cw[c * 4 + 2], w3 = cw[c * 4 + 3];
  float acc = cb[c] + w3 * basep[0];
  if (t > 0) acc += w2 * basep[-(ptrdiff_t)C_];
  if (t > 1) acc += w1 * basep[-2 * (ptrdiff_t)C_];
  if (t > 2) acc += w0 * basep[-3 * (ptrdiff_t)C_];
  float s = 1.f / (1.f + expf(-acc));
  outp[(((size_t)b * H_ + h) * T_ + t) * HD_ + d] = acc * s;
}

// ---------------------------------------------------------------------------
// g = log(clip(sigmoid(a),1e-6)), cumsum within chunk -> gc (B,H,T,HD).
// grid = B*H*NT (n fastest), 128 threads (d).
// ---------------------------------------------------------------------------
__global__ __launch_bounds__(128) void gc_kernel(
    const float* __restrict__ a_full, float* __restrict__ gc) {
  int idx = blockIdx.x;
  int n = idx & 31;
  int h = (idx >> 5) & 7;
  int b = idx >> 8;
  int d = threadIdx.x;
  float run = 0.f;
  for (int i = 0; i < BT_; ++i) {
    int t = n * BT_ + i;
    float a = a_full[(size_t)(b * T_ + t) * C_ + h * HD_ + d];
    float s = 1.f / (1.f + expf(-a));
    s = fmaxf(s, 1e-6f);
    run += logf(s);
    gc[(((size_t)b * H_ + h) * T_ + t) * HD_ + d] = run;
  }
}

// qg = q*e^gc (in place), kp = k*e^gc (in place), km = k*e^{-gc}
__global__ __launch_bounds__(256) void scale_qkk(
    float* __restrict__ q, float* __restrict__ k, float* __restrict__ km,
    const float* __restrict__ gc) {
  size_t i = (size_t)blockIdx.x * 256 + threadIdx.x;
  float g = gc[i];
  float e = expf(g);
  float ei = expf(-g);
  q[i] *= e;
  float kv = k[i];
  k[i] = kv * e;
  km[i] = kv * ei;
}

// ---------------------------------------------------------------------------
// Per-chunk pair dot products:
//  flavor 0: Akk[i][j] = sum_d km[i,d]*kp[j,d]   (strict lower, else 0)
//  flavor 1: Aqk[i][j] = sum_d qg[i,d]*km[j,d]   (incl diag lower, else 0)
// grid = (B*H*NT, 2), 256 threads, each thread a 4x4 block of pairs.
// ---------------------------------------------------------------------------
__global__ __launch_bounds__(256) void pairdot(
    const float* __restrict__ qg, const float* __restrict__ kp,
    const float* __restrict__ km, float* __restrict__ Akk, float* __restrict__ Aqk) {
  __shared__ float Xs[BT_][HD_];
  __shared__ float Ys[BT_][HD_];
  int bhn = blockIdx.x;
  int flavor = blockIdx.y;
  int bh = bhn >> 5, n = bhn & 31;
  size_t base = ((size_t)bh * T_ + (size_t)n * BT_) * HD_;
  const float* X = (flavor == 0 ? km : qg) + base;
  const float* Y = (flavor == 0 ? kp : km) + base;
  int tid = threadIdx.x;
#pragma unroll
  for (int s = 0; s < 8; ++s) {
    int fi = tid + s * 256;         // float4 index 0..2047
    int row = fi >> 5;
    int col = (fi & 31) * 4;
    *(float4*)&Xs[row][col] = *(const float4*)(X + (size_t)row * HD_ + col);
    *(float4*)&Ys[row][col] = *(const float4*)(Y + (size_t)row * HD_ + col);
  }
  __syncthreads();
  int i0 = (tid >> 4) * 4, j0 = (tid & 15) * 4;
  float acc[4][4];
#pragma unroll
  for (int r = 0; r < 4; ++r)
#pragma unroll
    for (int c2 = 0; c2 < 4; ++c2) acc[r][c2] = 0.f;
  if (j0 <= i0 + 3) {
    for (int dd = 0; dd < HD_; dd += 4) {
      float4 xr[4], yr[4];
#pragma unroll
      for (int r = 0; r < 4; ++r) xr[r] = *(const float4*)&Xs[i0 + r][dd];
#pragma unroll
      for (int c2 = 0; c2 < 4; ++c2) yr[c2] = *(const float4*)&Ys[j0 + c2][dd];
#pragma unroll
      for (int r = 0; r < 4; ++r)
#pragma unroll
        for (int c2 = 0; c2 < 4; ++c2)
          acc[r][c2] += xr[r].x * yr[c2].x + xr[r].y * yr[c2].y +
                        xr[r].z * yr[c2].z + xr[r].w * yr[c2].w;
    }
  }
  float* dst = (flavor == 0 ? Akk : Aqk) + (size_t)bhn * BT_ * BT_;
  int cut = (flavor == 0) ? 1 : 0;   // flavor0: j<i ; flavor1: j<=i
#pragma unroll
  for (int r = 0; r < 4; ++r)
#pragma unroll
    for (int c2 = 0; c2 < 4; ++c2) {
      int i = i0 + r, j = j0 + c2;
      float vdl = (j <= i - cut) ? acc[r][c2] : 0.f;
      dst[i * BT_ + j] = vdl;
    }
}

// ---------------------------------------------------------------------------
// Unit-lower-triangular solve (I+Akk) sol = rhs, forward substitution.
// Columns are independent -> 1 thread per column, no barriers in the loop.
// grid=(B*H*NT, 2): half 0 solves kp -> w_, half 1 solves v -> u. 128 thr.
// ---------------------------------------------------------------------------
__global__ __launch_bounds__(128) void solvek(
    const float* __restrict__ Akk, const float* __restrict__ kp,
    const float* __restrict__ v, float* __restrict__ w_, float* __restrict__ u) {
  __shared__ float A_s[BT_][BT_];
  __shared__ float sol[BT_][HD_];
  int bhn = blockIdx.x;
  int half = blockIdx.y;
  int tid = threadIdx.x;
  const float* Ab = Akk + (size_t)bhn * BT_ * BT_;
#pragma unroll
  for (int s = 0; s < 32; ++s) {
    int e = tid + s * 128;
    ((float*)A_s)[e] = Ab[e];
  }
  int bh = bhn >> 5, n = bhn & 31;
  size_t base = ((size_t)bh * T_ + (size_t)n * BT_) * HD_;
  const float* rhs = (half ? v : kp) + base;
  float* dst = (half ? u : w_) + base;
  for (int i = 0; i < BT_; ++i) sol[i][tid] = rhs[(size_t)i * HD_ + tid];
  __syncthreads();
  for (int i = 1; i < BT_; ++i) {
    float s = sol[i][tid];
    for (int j = 0; j < i; ++j) s -= A_s[i][j] * sol[j][tid];
    sol[i][tid] = s;
  }
  for (int i = 0; i < BT_; ++i) dst[(size_t)i * HD_ + tid] = sol[i][tid];
}

// ---------------------------------------------------------------------------
// P[kd][vd] = sum_i km[i,kd] * u[i,vd]  per chunk.  grid=B*H*NT, 256 thr,
// each thread an 8x8 output block.
// ---------------------------------------------------------------------------
__global__ __launch_bounds__(256) void ppre_k(
    const float* __restrict__ km, const float* __restrict__ u, float* __restrict__ P) {
  __shared__ float Ks[BT_][HD_];
  __shared__ float Us[BT_][HD_];
  int bhn = blockIdx.x;
  int bh = bhn >> 5, n = bhn & 31;
  size_t base = ((size_t)bh * T_ + (size_t)n * BT_) * HD_;
  int tid = threadIdx.x;
#pragma unroll
  for (int s = 0; s < 8; ++s) {
    int fi = tid + s * 256;
    int row = fi >> 5;
    int col = (fi & 31) * 4;
    *(float4*)&Ks[row][col] = *(const float4*)(km + base + (size_t)row * HD_ + col);
    *(float4*)&Us[row][col] = *(const float4*)(u + base + (size_t)row * HD_ + col);
  }
  __syncthreads();
  int kd0 = (tid >> 4) * 8, vd0 = (tid & 15) * 8;
  float acc[8][8];
#pragma unroll
  for (int a = 0; a < 8; ++a)
#pragma unroll
    for (int b2 = 0; b2 < 8; ++b2) acc[a][b2] = 0.f;
  for (int i = 0; i < BT_; ++i) {
    float kv[8], uv[8];
    *(float4*)(kv)     = *(const float4*)&Ks[i][kd0];
    *(float4*)(kv + 4) = *(const float4*)&Ks[i][kd0 + 4];
    *(float4*)(uv)     = *(const float4*)&Us[i][vd0];
    *(float4*)(uv + 4) = *(const float4*)&Us[i][vd0 + 4];
#pragma unroll
    for (int a = 0; a < 8; ++a)
#pragma unroll
      for (int b2 = 0; b2 < 8; ++b2)
        acc[a][b2] = fmaf(kv[a], uv[b2], acc[a][b2]);
  }
  float* dst = P + (size_t)bhn * HD_ * HD_;
#pragma unroll
  for (int a = 0; a < 8; ++a) {
    float4 v0 = make_float4(acc[a][0], acc[a][1], acc[a][2], acc[a][3]);
    float4 v1 = make_float4(acc[a][4], acc[a][5], acc[a][6], acc[a][7]);
    *(float4*)(dst + (size_t)(kd0 + a) * HD_ + vd0) = v0;
    *(float4*)(dst + (size_t)(kd0 + a) * HD_ + vd0 + 4) = v1;
  }
}

// ---------------------------------------------------------------------------
// Diagonal chunk scan (in place): P[n] becomes S_state[n] (state BEFORE chunk
// n); final state written to Sout.  S_{n+1} = e_last_n ⊙ (S_n + P_n).
// grid = B*H*HD (kd fastest), 128 threads (vd).
// ---------------------------------------------------------------------------
__global__ __launch_bounds__(128) void scan_k(
    float* __restrict__ P, const float* __restrict__ gc, float* __restrict__ Sout) {
  int kd = blockIdx.x & 127;
  int bh = blockIdx.x >> 7;
  int vd = threadIdx.x;
  float s = 0.f;
  for (int n = 0; n < NT_; ++n) {
    size_t idx = (((size_t)bh * NT_ + n) * HD_ + kd) * HD_ + vd;
    float p = P[idx];
    P[idx] = s;
    float gl = gc[((size_t)bh * T_ + n * BT_ + (BT_ - 1)) * HD_ + kd];
    s = (s + p) * expf(gl);
  }
  Sout[((size_t)bh * HD_ + kd) * HD_ + vd] = s;
}

// ---------------------------------------------------------------------------
// T = u - w @ S_n  per chunk.  grid=B*H*NT, 256 thr, 4x8 outputs each.
// S_n streamed from global (L1/L2 reuse), w in LDS.
// ---------------------------------------------------------------------------
__global__ __launch_bounds__(256) void tker(
    const float* __restrict__ w_, const float* __restrict__ u,
    const float* __restrict__ Sst, float* __restrict__ Tb) {
  __shared__ float Ws[BT_][HD_];
  int bhn = blockIdx.x;
  int bh = bhn >> 5, n = bhn & 31;
  size_t base = ((size_t)bh * T_ + (size_t)n * BT_) * HD_;
  int tid = threadIdx.x;
#pragma unroll
  for (int s = 0; s < 8; ++s) {
    int fi = tid + s * 256;
    if (fi < 2048) {
      int row = fi >> 5;
      int col = (fi & 31) * 4;
      *(float4*)&Ws[row][col] = *(const float4*)(w_ + base + (size_t)row * HD_ + col);
    }
  }
  __syncthreads();
  const float* S = Sst + (size_t)bhn * HD_ * HD_;
  int i0 = (tid >> 4) * 4, vd0 = (tid & 15) * 8;
  float acc[4][8];
#pragma unroll
  for (int r = 0; r < 4; ++r)
#pragma unroll
    for (int c2 = 0; c2 < 8; ++c2) acc[r][c2] = 0.f;
  for (int kd = 0; kd < HD_; ++kd) {
    float sv[8];
    *(float4*)(sv)     = *(const float4*)(S + (size_t)kd * HD_ + vd0);
    *(float4*)(sv + 4) = *(const float4*)(S + (size_t)kd * HD_ + vd0 + 4);
#pragma unroll
    for (int r = 0; r < 4; ++r) {
      float wv = Ws[i0 + r][kd];
#pragma unroll
      for (int c2 = 0; c2 < 8; ++c2) acc[r][c2] = fmaf(wv, sv[c2], acc[r][c2]);
    }
  }
#pragma unroll
  for (int r = 0; r < 4; ++r) {
    const float* up = u + base + (size_t)(i0 + r) * HD_ + vd0;
    float* tp = Tb + base + (size_t)(i0 + r) * HD_ + vd0;
    float4 u0 = *(const float4*)(up);
    float4 u1 = *(const float4*)(up + 4);
    float4 t0 = make_float4(u0.x - acc[r][0], u0.y - acc[r][1], u0.z - acc[r][2], u0.w - acc[r][3]);
    float4 t1 = make_float4(u1.x - acc[r][4], u1.y - acc[r][5], u1.z - acc[r][6], u1.w - acc[r][7]);
    *(float4*)(tp) = t0;
    *(float4*)(tp + 4) = t1;
  }
}

// ---------------------------------------------------------------------------
// o = qg @ S_n + Aqk @ T  per chunk.  grid=B*H*NT, 256 thr, 4x8 outputs.
// qg + Aqk in LDS; S_n and T streamed from global.
// ---------------------------------------------------------------------------
__global__ __launch_bounds__(256) void oker(
    const float* __restrict__ qg, const float* __restrict__ Aqk,
    const float* __restrict__ Sst, const float* __restrict__ Tb, float* __restrict__ o) {
  __shared__ float Qs[BT_][HD_];
  __shared__ float As2[BT_][BT_];
  int bhn = blockIdx.x;
  int bh = bhn >> 5, n = bhn & 31;
  size_t base = ((size_t)bh * T_ + (size_t)n * BT_) * HD_;
  int tid = threadIdx.x;
#pragma unroll
  for (int s = 0; s < 8; ++s) {
    int fi = tid + s * 256;
    int row = fi >> 5;
    int col = (fi & 31) * 4;
    *(float4*)&Qs[row][col] = *(const float4*)(qg + base + (size_t)row * HD_ + col);
  }
  const float* Ap = Aqk + (size_t)bhn * BT_ * BT_;
#pragma unroll
  for (int s = 0; s < 16; ++s) {
    int e = tid + s * 256;
    ((float*)As2)[e] = Ap[e];
  }
  __syncthreads();
  const float* S = Sst + (size_t)bhn * HD_ * HD_;
  int i0 = (tid >> 4) * 4, vd0 = (tid & 15) * 8;
  float acc[4][8];
#pragma unroll
  for (int r = 0; r < 4; ++r)
#pragma unroll
    for (int c2 = 0; c2 < 8; ++c2) acc[r][c2] = 0.f;
  for (int kd = 0; kd < HD_; ++kd) {
    float sv[8];
    *(float4*)(sv)     = *(const float4*)(S + (size_t)kd * HD_ + vd0);
    *(float4*)(sv + 4) = *(const float4*)(S + (size_t)kd * HD_ + vd0 + 4);
#pragma unroll
    for (int r = 0; r < 4; ++r) {
      float qv = Qs[i0 + r][kd];
#pragma unroll
      for (int c2 = 0; c2 < 8; ++c2) acc[r][c2] = fmaf(qv, sv[c2], acc[r][c2]);
    }
  }
  for (int j = 0; j < BT_; ++j) {
    float tv[8];
    const float* tp = Tb + base + (size_t)j * HD_ + vd0;
    *(float4*)(tv)     = *(const float4*)(tp);
    *(float4*)(tv + 4) = *(const float4*)(tp + 4);
#pragma unroll
    for (int r = 0; r < 4; ++r) {
      float av = As2[i0 + r][j];
#pragma unroll
      for (int c2 = 0; c2 < 8; ++c2) acc[r][c2] = fmaf(av, tv[c2], acc[r][c2]);
    }
  }
#pragma unroll
  for (int r = 0; r < 4; ++r) {
    float* op = o + base + (size_t)(i0 + r) * HD_ + vd0;
    float4 v0 = make_float4(acc[r][0], acc[r][1], acc[r][2], acc[r][3]);
    float4 v1 = make_float4(acc[r][4], acc[r][5], acc[r][6], acc[r][7]);
    *(float4*)(op) = v0;
    *(float4*)(op + 4) = v1;
  }
}

// ---------------------------------------------------------------------------
// Epilogue: transpose (B,H,T,HD)->(B,T,C), RMS-norm over HD, *norm_w, *gate.
// grid = B*T*H (h fastest), 128 threads.
// ---------------------------------------------------------------------------
__global__ __launch_bounds__(128) void epi(
    const float* __restrict__ o, const float* __restrict__ gatef,
    const float* __restrict__ normw, float* __restrict__ o2) {
  int idx = blockIdx.x;
  int h = idx & 7;
  int t = (idx >> 3) & (T_ - 1);
  int b = idx >> 14;
  int d = threadIdx.x;
  float val = o[(((size_t)b * H_ + h) * T_ + t) * HD_ + d];
  float ss = val * val;
#pragma unroll
  for (int off = 32; off > 0; off >>= 1) ss += __shfl_down(ss, off);
  __shared__ float red[2];
  if ((d & 63) == 0) red[d >> 6] = ss;
  __syncthreads();
  float tot = red[0] + red[1];
  float ms = tot * (1.f / HD_);
  float r = rsqrtf(ms + EPS_RMS);
  float gv = gatef[(size_t)(b * T_ + t) * C_ + h * HD_ + d];
  float sig = 1.f / (1.f + expf(-gv));
  o2[(size_t)(b * T_ + t) * C_ + h * HD_ + d] = val * r * normw[d] * sig;
}

// ---------------------------------------------------------------------------
extern "C" void kernel_launch(void* const* d_in, const int* in_sizes, int n_in,
                              void* d_out, int out_size, void* d_ws, size_t ws_size,
                              hipStream_t stream) {
  (void)in_sizes; (void)n_in; (void)out_size;
  const float* x    = (const float*)d_in[0];
  const float* Wq   = (const float*)d_in[1];
  const float* Wk   = (const float*)d_in[2];
  const float* Wv   = (const float*)d_in[3];
  const float* cqw  = (const float*)d_in[4];
  const float* cqb  = (const float*)d_in[5];
  const float* ckw  = (const float*)d_in[6];
  const float* ckb  = (const float*)d_in[7];
  const float* cvw  = (const float*)d_in[8];
  const float* cvb  = (const float*)d_in[9];
  const float* Wad  = (const float*)d_in[10];
  const float* Wau  = (const float*)d_in[11];
  // d_in[12] = Wb : dead code in reference
  const float* Wgd  = (const float*)d_in[13];
  const float* Wgu  = (const float*)d_in[14];
  const float* normw= (const float*)d_in[15];
  const float* Wo   = (const float*)d_in[16];

  float* outp = (float*)d_out;                 // (B,T,D) = 8,388,608 floats
  float* Sout = outp + (size_t)M_ * D_;        // (B,H,HD,HD) = 262,144 floats

  const size_t SZ = (size_t)M_ * C_;           // 4,194,304
  const size_t LOWSZ = (size_t)M_ * HD_;       // 524,288
  const size_t ASZ = (size_t)B_ * H_ * NT_ * BT_ * BT_;   // 2,097,152
  const size_t PSZ = (size_t)B_ * H_ * NT_ * HD_ * HD_;   // 8,388,608

  float* ws = (float*)d_ws;
  float* q_pre  = ws;
  float* k_pre  = ws + SZ;
  float* v_pre  = ws + 2 * SZ;
  float* ad_low = ws + 3 * SZ;
  float* gd_low = ad_low + LOWSZ;
  float* a_full = gd_low + LOWSZ;
  float* gatef  = a_full + SZ;
  float* qg     = gatef + SZ;
  float* kp     = qg + SZ;
  float* km     = kp + SZ;
  float* vv     = km + SZ;
  float* gc     = vv + SZ;
  float* w_     = gc + SZ;
  float* u      = w_ + SZ;
  float* Ppre   = u + SZ;
  // reuse (lifetimes disjoint):
  float* Akk = k_pre;          // k_pre dead after conv_norm_head(k)
  float* Aqk = k_pre + ASZ;
  float* Tb  = a_full;         // a_full dead after gc_kernel
  float* ob  = v_pre;          // v_pre dead after conv_silu_head
  float* o2  = q_pre;          // q_pre dead after conv_norm_head(q)

  size_t need = ((size_t)(Ppre - ws) + PSZ) * sizeof(float);
  if (ws_size < need) return;  // insufficient scratch; bail (will fail check)

  // Phase 1: projections
  gemm_f32<<<dim3(C_ / GT, M_ / GT), 256, 0, stream>>>(x, Wq, q_pre, C_, D_);
  gemm_f32<<<dim3(C_ / GT, M_ / GT), 256, 0, stream>>>(x, Wk, k_pre, C_, D_);
  gemm_f32<<<dim3(C_ / GT, M_ / GT), 256, 0, stream>>>(x, Wv, v_pre, C_, D_);
  hipMemsetAsync(ad_low, 0, 2 * LOWSZ * sizeof(float), stream);
  gemm_f32_splitk<<<dim3(1, M_ / GT, 8), 256, 0, stream>>>(x, Wad, ad_low, HD_, D_, D_ / 8);
  gemm_f32_splitk<<<dim3(1, M_ / GT, 8), 256, 0, stream>>>(x, Wgd, gd_low, HD_, D_, D_ / 8);
  gemm_f32<<<dim3(C_ / GT, M_ / GT), 256, 0, stream>>>(ad_low, Wau, a_full, C_, HD_);
  gemm_f32<<<dim3(C_ / GT, M_ / GT), 256, 0, stream>>>(gd_low, Wgu, gatef, C_, HD_);

  // Phase 2: conv + heads
  conv_norm_head<<<B_ * T_ * H_, 128, 0, stream>>>(q_pre, cqw, cqb, qg);
  conv_norm_head<<<B_ * T_ * H_, 128, 0, stream>>>(k_pre, ckw, ckb, kp);
  conv_silu_head<<<B_ * T_ * H_, 128, 0, stream>>>(v_pre, cvw, cvb, vv);

  // Phase 3: decay cumsum + scaled q/k variants
  gc_kernel<<<B_ * H_ * NT_, 128, 0, stream>>>(a_full, gc);
  scale_qkk<<<(int)(SZ / 256), 256, 0, stream>>>(qg, kp, km, gc);

  // Phase 4: per-chunk matrices + triangular solve
  pairdot<<<dim3(B_ * H_ * NT_, 2), 256, 0, stream>>>(qg, kp, km, Akk, Aqk);
  solvek<<<dim3(B_ * H_ * NT_, 2), 128, 0, stream>>>(Akk, kp, vv, w_, u);

  // Phase 5: state scan
  ppre_k<<<B_ * H_ * NT_, 256, 0, stream>>>(km, u, Ppre);
  scan_k<<<B_ * H_ * HD_, 128, 0, stream>>>(Ppre, gc, Sout);

  // Phase 6: outputs
  tker<<<B_ * H_ * NT_, 256, 0, stream>>>(w_, u, Ppre, Tb);
  oker<<<B_ * H_ * NT_, 256, 0, stream>>>(qg, Aqk, Ppre, Tb, ob);
  epi<<<B_ * T_ * H_, 128, 0, stream>>>(ob, gatef, normw, o2);
  gemm_f32<<<dim3(D_ / GT, M_ / GT), 256, 0, stream>>>(o2, Wo, outp, D_, C_);
}

// Round 2
// 591.499 us; speedup vs baseline: 2.7987x; 2.7987x over previous
//
#include <hip/hip_runtime.h>
#include <hip/hip_bf16.h>
#include <cstdint>
#include <cstddef>

// Problem constants
constexpr int B_  = 2;
constexpr int T_  = 2048;
constexpr int D_  = 2048;
constexpr int H_  = 8;
constexpr int HD_ = 128;
constexpr int C_  = 1024;   // H*HD
constexpr int BT_ = 64;
constexpr int NT_ = 32;     // T/BT
constexpr int M_  = 4096;   // B*T
constexpr float EPS_RMS = 1.1920929e-07f;

typedef __bf16 bf16x8 __attribute__((ext_vector_type(8)));
typedef float f32x4 __attribute__((ext_vector_type(4)));

typedef const __attribute__((address_space(1))) unsigned int* gptr_t;
typedef __attribute__((address_space(3))) unsigned int* lptr_t;

__device__ __forceinline__ void gload16(const void* g, void* l) {
  __builtin_amdgcn_global_load_lds((gptr_t)g, (lptr_t)l, 16, 0, 0);
}

// ---------------------------------------------------------------------------
// bf16 MFMA GEMM (m97 structure): C[M,N] = A[M,K] @ Bt[N,K]^T
// A row-major (lda=K), Bt row-major (ldb=K), C row-major (ldc=N).
// 128x128 tile, BK=32, 256 threads = 4 waves (2x2), each wave 64x64 via
// 4x4 grid of 16x16x32 MFMAs.  Staging via global_load_lds width=16.
// M%128==0, N%128==0, K%32==0.
// ---------------------------------------------------------------------------
template <typename OutT>
__global__ __launch_bounds__(256) void gemm_bf16k(
    const __hip_bfloat16* __restrict__ A, const __hip_bfloat16* __restrict__ Bt,
    OutT* __restrict__ C, int N, int K) {
  __shared__ __hip_bfloat16 sA[128 * 32];
  __shared__ __hip_bfloat16 sB[128 * 32];
  const int tid = threadIdx.x;
  const int lane = tid & 63;
  const int m0 = blockIdx.y * 128, n0 = blockIdx.x * 128;
  const int wm = ((tid >> 6) >> 1) * 64, wn = ((tid >> 6) & 1) * 64;
  f32x4 acc[4][4];
#pragma unroll
  for (int i = 0; i < 4; ++i)
#pragma unroll
    for (int j = 0; j < 4; ++j) acc[i][j] = (f32x4)(0.f);
  // staging: 512 16B-chunks per tile; thread handles chunks tid and tid+256.
  const int f0 = tid, f1 = tid + 256;
  const int r0 = f0 >> 2, c0 = (f0 & 3) * 8;
  const int r1 = f1 >> 2, c1 = (f1 & 3) * 8;
  const size_t aoff0 = (size_t)(m0 + r0) * K + c0;
  const size_t aoff1 = (size_t)(m0 + r1) * K + c1;
  const size_t boff0 = (size_t)(n0 + r0) * K + c0;
  const size_t boff1 = (size_t)(n0 + r1) * K + c1;
  const int lr = lane & 15, lk = (lane >> 4) * 8;
  for (int k0 = 0; k0 < K; k0 += 32) {
    __syncthreads();
    gload16(A + aoff0 + k0, &sA[f0 * 8]);
    gload16(A + aoff1 + k0, &sA[f1 * 8]);
    gload16(Bt + boff0 + k0, &sB[f0 * 8]);
    gload16(Bt + boff1 + k0, &sB[f1 * 8]);
    __syncthreads();
    bf16x8 af[4], bfr[4];
#pragma unroll
    for (int i = 0; i < 4; ++i)
      af[i] = *(const bf16x8*)&sA[(wm + i * 16 + lr) * 32 + lk];
#pragma unroll
    for (int j = 0; j < 4; ++j)
      bfr[j] = *(const bf16x8*)&sB[(wn + j * 16 + lr) * 32 + lk];
#pragma unroll
    for (int i = 0; i < 4; ++i)
#pragma unroll
      for (int j = 0; j < 4; ++j)
        acc[i][j] = __builtin_amdgcn_mfma_f32_16x16x32_bf16(af[i], bfr[j], acc[i][j], 0, 0, 0);
  }
  // epilogue: C/D layout col=lane&15, row=(lane>>4)*4+reg
  const int er = (lane >> 4) * 4, ec = lane & 15;
#pragma unroll
  for (int i = 0; i < 4; ++i) {
#pragma unroll
    for (int j = 0; j < 4; ++j) {
      int row = m0 + wm + i * 16 + er;
      int col = n0 + wn + j * 16 + ec;
#pragma unroll
      for (int r = 0; r < 4; ++r) {
        float v = acc[i][j][r];
        if constexpr (sizeof(OutT) == 2)
          C[(size_t)(row + r) * N + col] = __float2bfloat16(v);
        else
          C[(size_t)(row + r) * N + col] = v;
      }
    }
  }
}

// Split-K variant: grid.z slabs, each writes its own f32 slab (no atomics).
__global__ __launch_bounds__(256) void gemm_bf16_sk(
    const __hip_bfloat16* __restrict__ A, const __hip_bfloat16* __restrict__ Bt,
    float* __restrict__ Cp, int N, int K, int KS) {
  __shared__ __hip_bfloat16 sA[128 * 32];
  __shared__ __hip_bfloat16 sB[128 * 32];
  const int tid = threadIdx.x;
  const int lane = tid & 63;
  const int m0 = blockIdx.y * 128, n0 = blockIdx.x * 128;
  const int wm = ((tid >> 6) >> 1) * 64, wn = ((tid >> 6) & 1) * 64;
  const int kb = blockIdx.z * KS;
  float* Cs = Cp + (size_t)blockIdx.z * ((size_t)gridDim.y * 128) * N;
  f32x4 acc[4][4];
#pragma unroll
  for (int i = 0; i < 4; ++i)
#pragma unroll
    for (int j = 0; j < 4; ++j) acc[i][j] = (f32x4)(0.f);
  const int f0 = tid, f1 = tid + 256;
  const int r0 = f0 >> 2, c0 = (f0 & 3) * 8;
  const int r1 = f1 >> 2, c1 = (f1 & 3) * 8;
  const size_t aoff0 = (size_t)(m0 + r0) * K + c0;
  const size_t aoff1 = (size_t)(m0 + r1) * K + c1;
  const size_t boff0 = (size_t)(n0 + r0) * K + c0;
  const size_t boff1 = (size_t)(n0 + r1) * K + c1;
  const int lr = lane & 15, lk = (lane >> 4) * 8;
  for (int k0 = kb; k0 < kb + KS; k0 += 32) {
    __syncthreads();
    gload16(A + aoff0 + k0, &sA[f0 * 8]);
    gload16(A + aoff1 + k0, &sA[f1 * 8]);
    gload16(Bt + boff0 + k0, &sB[f0 * 8]);
    gload16(Bt + boff1 + k0, &sB[f1 * 8]);
    __syncthreads();
    bf16x8 af[4], bfr[4];
#pragma unroll
    for (int i = 0; i < 4; ++i)
      af[i] = *(const bf16x8*)&sA[(wm + i * 16 + lr) * 32 + lk];
#pragma unroll
    for (int j = 0; j < 4; ++j)
      bfr[j] = *(const bf16x8*)&sB[(wn + j * 16 + lr) * 32 + lk];
#pragma unroll
    for (int i = 0; i < 4; ++i)
#pragma unroll
      for (int j = 0; j < 4; ++j)
        acc[i][j] = __builtin_amdgcn_mfma_f32_16x16x32_bf16(af[i], bfr[j], acc[i][j], 0, 0, 0);
  }
  const int er = (lane >> 4) * 4, ec = lane & 15;
#pragma unroll
  for (int i = 0; i < 4; ++i)
#pragma unroll
    for (int j = 0; j < 4; ++j) {
      int row = m0 + wm + i * 16 + er;
      int col = n0 + wn + j * 16 + ec;
#pragma unroll
      for (int r = 0; r < 4; ++r)
        Cs[(size_t)(row + r) * N + col] = acc[i][j][r];
    }
}

// Reduce 4 split-K slabs (M x 256) and split into ad_bf / gd_bf (M x 128 each).
__global__ __launch_bounds__(256) void reduce_dg(
    const float* __restrict__ slabs, __hip_bfloat16* __restrict__ adb,
    __hip_bfloat16* __restrict__ gdb) {
  int idx = blockIdx.x * 256 + threadIdx.x;
  int m = idx >> 8, c = idx & 255;
  const size_t ss = (size_t)M_ * 256;
  float s = slabs[idx] + slabs[idx + ss] + slabs[idx + 2 * ss] + slabs[idx + 3 * ss];
  if (c < 128) adb[(size_t)m * 128 + c] = __float2bfloat16(s);
  else         gdb[(size_t)m * 128 + (c - 128)] = __float2bfloat16(s);
}

// f32 -> bf16 elementwise (n must be multiple of 1024; 4 elems/thread)
__global__ __launch_bounds__(256) void cvt_bf(
    const float* __restrict__ in, __hip_bfloat16* __restrict__ out) {
  size_t i = ((size_t)blockIdx.x * 256 + threadIdx.x) * 4;
  float4 v = *(const float4*)(in + i);
  out[i + 0] = __float2bfloat16(v.x);
  out[i + 1] = __float2bfloat16(v.y);
  out[i + 2] = __float2bfloat16(v.z);
  out[i + 3] = __float2bfloat16(v.w);
}

// Transpose-convert: W (K,N) f32 -> Wt (N,K) bf16.  grid (N/32, K/32), 256 thr.
__global__ __launch_bounds__(256) void tconv(
    const float* __restrict__ W, __hip_bfloat16* __restrict__ Wt, int K, int N) {
  __shared__ float tile[32][33];
  int tx = threadIdx.x & 31, ty = threadIdx.x >> 5;  // ty 0..7
  int kb = blockIdx.y * 32, nb = blockIdx.x * 32;
#pragma unroll
  for (int s = 0; s < 4; ++s) {
    int kk = ty + s * 8;
    tile[kk][tx] = W[(size_t)(kb + kk) * N + nb + tx];
  }
  __syncthreads();
#pragma unroll
  for (int s = 0; s < 4; ++s) {
    int nn = ty + s * 8;
    Wt[(size_t)(nb + nn) * K + kb + tx] = __float2bfloat16(tile[tx][nn]);
  }
}

// ---------------------------------------------------------------------------
// Causal depthwise conv (window 4) + bias on bf16 pre-activations (row stride
// 3C within the fused qkv buffer), then per-(b,t,h) L2 normalize, write f32
// (B,H,T,HD).  grid = B*T*H (h fastest), 128 threads.
// ---------------------------------------------------------------------------
__global__ __launch_bounds__(128) void conv_norm_bf(
    const __hip_bfloat16* __restrict__ pre, const float* __restrict__ cw,
    const float* __restrict__ cb, float* __restrict__ outp) {
  int idx = blockIdx.x;
  int h = idx & 7;
  int t = (idx >> 3) & (T_ - 1);
  int b = idx >> 14;
  int d = threadIdx.x;
  int c = h * HD_ + d;
  const __hip_bfloat16* p = pre + (size_t)(b * T_ + t) * (3 * C_) + c;
  float w0 = cw[c * 4 + 0], w1 = cw[c * 4 + 1], w2 = cw[c * 4 + 2], w3 = cw[c * 4 + 3];
  float acc = cb[c] + w3 * __bfloat162float(p[0]);
  if (t > 0) acc += w2 * __bfloat162float(p[-(ptrdiff_t)(3 * C_)]);
  if (t > 1) acc += w1 * __bfloat162float(p[-2 * (ptrdiff_t)(3 * C_)]);
  if (t > 2) acc += w0 * __bfloat162float(p[-3 * (ptrdiff_t)(3 * C_)]);
  float ss = acc * acc;
#pragma unroll
  for (int o = 32; o > 0; o >>= 1) ss += __shfl_down(ss, o);
  __shared__ float red[2];
  if ((d & 63) == 0) red[d >> 6] = ss;
  __syncthreads();
  float tot = red[0] + red[1];
  float nrm = fmaxf(sqrtf(tot), 1e-12f);
  outp[(((size_t)b * H_ + h) * T_ + t) * HD_ + d] = acc / nrm;
}

__global__ __launch_bounds__(128) void conv_silu_bf(
    const __hip_bfloat16* __restrict__ pre, const float* __restrict__ cw,
    const float* __restrict__ cb, float* __restrict__ outp) {
  int idx = blockIdx.x;
  int h = idx & 7;
  int t = (idx >> 3) & (T_ - 1);
  int b = idx >> 14;
  int d = threadIdx.x;
  int c = h * HD_ + d;
  const __hip_bfloat16* p = pre + (size_t)(b * T_ + t) * (3 * C_) + c;
  float w0 = cw[c * 4 + 0], w1 = cw[c * 4 + 1], w2 = cw[c * 4 + 2], w3 = cw[c * 4 + 3];
  float acc = cb[c] + w3 * __bfloat162float(p[0]);
  if (t > 0) acc += w2 * __bfloat162float(p[-(ptrdiff_t)(3 * C_)]);
  if (t > 1) acc += w1 * __bfloat162float(p[-2 * (ptrdiff_t)(3 * C_)]);
  if (t > 2) acc += w0 * __bfloat162float(p[-3 * (ptrdiff_t)(3 * C_)]);
  float s = 1.f / (1.f + expf(-acc));
  outp[(((size_t)b * H_ + h) * T_ + t) * HD_ + d] = acc * s;
}

// ---------------------------------------------------------------------------
// g = log(clip(sigmoid(a),1e-6)), cumsum within chunk -> gc (B,H,T,HD)
// ---------------------------------------------------------------------------
__global__ __launch_bounds__(128) void gc_kernel(
    const float* __restrict__ a_full, float* __restrict__ gc) {
  int idx = blockIdx.x;
  int n = idx & 31;
  int h = (idx >> 5) & 7;
  int b = idx >> 8;
  int d = threadIdx.x;
  float run = 0.f;
  for (int i = 0; i < BT_; ++i) {
    int t = n * BT_ + i;
    float a = a_full[(size_t)(b * T_ + t) * C_ + h * HD_ + d];
    float s = 1.f / (1.f + expf(-a));
    s = fmaxf(s, 1e-6f);
    run += logf(s);
    gc[(((size_t)b * H_ + h) * T_ + t) * HD_ + d] = run;
  }
}

__global__ __launch_bounds__(256) void scale_qkk(
    float* __restrict__ q, float* __restrict__ k, float* __restrict__ km,
    const float* __restrict__ gc) {
  size_t i = (size_t)blockIdx.x * 256 + threadIdx.x;
  float g = gc[i];
  float e = expf(g);
  float ei = expf(-g);
  q[i] *= e;
  float kv = k[i];
  k[i] = kv * e;
  km[i] = kv * ei;
}

// ---------------------------------------------------------------------------
// Per-chunk pair dot products (Akk strict-lower, Aqk incl-diag lower)
// ---------------------------------------------------------------------------
__global__ __launch_bounds__(256) void pairdot(
    const float* __restrict__ qg, const float* __restrict__ kp,
    const float* __restrict__ km, float* __restrict__ Akk, float* __restrict__ Aqk) {
  __shared__ float Xs[BT_][HD_];
  __shared__ float Ys[BT_][HD_];
  int bhn = blockIdx.x;
  int flavor = blockIdx.y;
  int bh = bhn >> 5, n = bhn & 31;
  size_t base = ((size_t)bh * T_ + (size_t)n * BT_) * HD_;
  const float* X = (flavor == 0 ? km : qg) + base;
  const float* Y = (flavor == 0 ? kp : km) + base;
  int tid = threadIdx.x;
#pragma unroll
  for (int s = 0; s < 8; ++s) {
    int fi = tid + s * 256;
    int row = fi >> 5;
    int col = (fi & 31) * 4;
    *(float4*)&Xs[row][col] = *(const float4*)(X + (size_t)row * HD_ + col);
    *(float4*)&Ys[row][col] = *(const float4*)(Y + (size_t)row * HD_ + col);
  }
  __syncthreads();
  int i0 = (tid >> 4) * 4, j0 = (tid & 15) * 4;
  float acc[4][4];
#pragma unroll
  for (int r = 0; r < 4; ++r)
#pragma unroll
    for (int c2 = 0; c2 < 4; ++c2) acc[r][c2] = 0.f;
  if (j0 <= i0 + 3) {
    for (int dd = 0; dd < HD_; dd += 4) {
      float4 xr[4], yr[4];
#pragma unroll
      for (int r = 0; r < 4; ++r) xr[r] = *(const float4*)&Xs[i0 + r][dd];
#pragma unroll
      for (int c2 = 0; c2 < 4; ++c2) yr[c2] = *(const float4*)&Ys[j0 + c2][dd];
#pragma unroll
      for (int r = 0; r < 4; ++r)
#pragma unroll
        for (int c2 = 0; c2 < 4; ++c2)
          acc[r][c2] += xr[r].x * yr[c2].x + xr[r].y * yr[c2].y +
                        xr[r].z * yr[c2].z + xr[r].w * yr[c2].w;
    }
  }
  float* dst = (flavor == 0 ? Akk : Aqk) + (size_t)bhn * BT_ * BT_;
  int cut = (flavor == 0) ? 1 : 0;
#pragma unroll
  for (int r = 0; r < 4; ++r)
#pragma unroll
    for (int c2 = 0; c2 < 4; ++c2) {
      int i = i0 + r, j = j0 + c2;
      float vdl = (j <= i - cut) ? acc[r][c2] : 0.f;
      dst[i * BT_ + j] = vdl;
    }
}

// ---------------------------------------------------------------------------
// Unit-lower-triangular forward substitution; columns independent.
// ---------------------------------------------------------------------------
__global__ __launch_bounds__(128) void solvek(
    const float* __restrict__ Akk, const float* __restrict__ kp,
    const float* __restrict__ v, float* __restrict__ w_, float* __restrict__ u) {
  __shared__ float A_s[BT_][BT_];
  __shared__ float sol[BT_][HD_];
  int bhn = blockIdx.x;
  int half = blockIdx.y;
  int tid = threadIdx.x;
  const float* Ab = Akk + (size_t)bhn * BT_ * BT_;
#pragma unroll
  for (int s = 0; s < 32; ++s) {
    int e = tid + s * 128;
    ((float*)A_s)[e] = Ab[e];
  }
  int bh = bhn >> 5, n = bhn & 31;
  size_t base = ((size_t)bh * T_ + (size_t)n * BT_) * HD_;
  const float* rhs = (half ? v : kp) + base;
  float* dst = (half ? u : w_) + base;
  for (int i = 0; i < BT_; ++i) sol[i][tid] = rhs[(size_t)i * HD_ + tid];
  __syncthreads();
  for (int i = 1; i < BT_; ++i) {
    float s = sol[i][tid];
    for (int j = 0; j < i; ++j) s -= A_s[i][j] * sol[j][tid];
    sol[i][tid] = s;
  }
  for (int i = 0; i < BT_; ++i) dst[(size_t)i * HD_ + tid] = sol[i][tid];
}

// ---------------------------------------------------------------------------
// P[kd][vd] = sum_i km[i,kd] * u[i,vd]  per chunk
// ---------------------------------------------------------------------------
__global__ __launch_bounds__(256) void ppre_k(
    const float* __restrict__ km, const float* __restrict__ u, float* __restrict__ P) {
  __shared__ float Ks[BT_][HD_];
  __shared__ float Us[BT_][HD_];
  int bhn = blockIdx.x;
  int bh = bhn >> 5, n = bhn & 31;
  size_t base = ((size_t)bh * T_ + (size_t)n * BT_) * HD_;
  int tid = threadIdx.x;
#pragma unroll
  for (int s = 0; s < 8; ++s) {
    int fi = tid + s * 256;
    int row = fi >> 5;
    int col = (fi & 31) * 4;
    *(float4*)&Ks[row][col] = *(const float4*)(km + base + (size_t)row * HD_ + col);
    *(float4*)&Us[row][col] = *(const float4*)(u + base + (size_t)row * HD_ + col);
  }
  __syncthreads();
  int kd0 = (tid >> 4) * 8, vd0 = (tid & 15) * 8;
  float acc[8][8];
#pragma unroll
  for (int a = 0; a < 8; ++a)
#pragma unroll
    for (int b2 = 0; b2 < 8; ++b2) acc[a][b2] = 0.f;
  for (int i = 0; i < BT_; ++i) {
    float kv[8], uv[8];
    *(float4*)(kv)     = *(const float4*)&Ks[i][kd0];
    *(float4*)(kv + 4) = *(const float4*)&Ks[i][kd0 + 4];
    *(float4*)(uv)     = *(const float4*)&Us[i][vd0];
    *(float4*)(uv + 4) = *(const float4*)&Us[i][vd0 + 4];
#pragma unroll
    for (int a = 0; a < 8; ++a)
#pragma unroll
      for (int b2 = 0; b2 < 8; ++b2)
        acc[a][b2] = fmaf(kv[a], uv[b2], acc[a][b2]);
  }
  float* dst = P + (size_t)bhn * HD_ * HD_;
#pragma unroll
  for (int a = 0; a < 8; ++a) {
    float4 v0 = make_float4(acc[a][0], acc[a][1], acc[a][2], acc[a][3]);
    float4 v1 = make_float4(acc[a][4], acc[a][5], acc[a][6], acc[a][7]);
    *(float4*)(dst + (size_t)(kd0 + a) * HD_ + vd0) = v0;
    *(float4*)(dst + (size_t)(kd0 + a) * HD_ + vd0 + 4) = v1;
  }
}

// ---------------------------------------------------------------------------
// Diagonal chunk scan (in place)
// ---------------------------------------------------------------------------
__global__ __launch_bounds__(128) void scan_k(
    float* __restrict__ P, const float* __restrict__ gc, float* __restrict__ Sout) {
  int kd = blockIdx.x & 127;
  int bh = blockIdx.x >> 7;
  int vd = threadIdx.x;
  float s = 0.f;
  for (int n = 0; n < NT_; ++n) {
    size_t idx = (((size_t)bh * NT_ + n) * HD_ + kd) * HD_ + vd;
    float p = P[idx];
    P[idx] = s;
    float gl = gc[((size_t)bh * T_ + n * BT_ + (BT_ - 1)) * HD_ + kd];
    s = (s + p) * expf(gl);
  }
  Sout[((size_t)bh * HD_ + kd) * HD_ + vd] = s;
}

// ---------------------------------------------------------------------------
// T = u - w @ S_n  per chunk
// ---------------------------------------------------------------------------
__global__ __launch_bounds__(256) void tker(
    const float* __restrict__ w_, const float* __restrict__ u,
    const float* __restrict__ Sst, float* __restrict__ Tb) {
  __shared__ float Ws[BT_][HD_];
  int bhn = blockIdx.x;
  int bh = bhn >> 5, n = bhn & 31;
  size_t base = ((size_t)bh * T_ + (size_t)n * BT_) * HD_;
  int tid = threadIdx.x;
#pragma unroll
  for (int s = 0; s < 8; ++s) {
    int fi = tid + s * 256;
    if (fi < 2048) {
      int row = fi >> 5;
      int col = (fi & 31) * 4;
      *(float4*)&Ws[row][col] = *(const float4*)(w_ + base + (size_t)row * HD_ + col);
    }
  }
  __syncthreads();
  const float* S = Sst + (size_t)bhn * HD_ * HD_;
  int i0 = (tid >> 4) * 4, vd0 = (tid & 15) * 8;
  float acc[4][8];
#pragma unroll
  for (int r = 0; r < 4; ++r)
#pragma unroll
    for (int c2 = 0; c2 < 8; ++c2) acc[r][c2] = 0.f;
  for (int kd = 0; kd < HD_; ++kd) {
    float sv[8];
    *(float4*)(sv)     = *(const float4*)(S + (size_t)kd * HD_ + vd0);
    *(float4*)(sv + 4) = *(const float4*)(S + (size_t)kd * HD_ + vd0 + 4);
#pragma unroll
    for (int r = 0; r < 4; ++r) {
      float wv = Ws[i0 + r][kd];
#pragma unroll
      for (int c2 = 0; c2 < 8; ++c2) acc[r][c2] = fmaf(wv, sv[c2], acc[r][c2]);
    }
  }
#pragma unroll
  for (int r = 0; r < 4; ++r) {
    const float* up = u + base + (size_t)(i0 + r) * HD_ + vd0;
    float* tp = Tb + base + (size_t)(i0 + r) * HD_ + vd0;
    float4 u0 = *(const float4*)(up);
    float4 u1 = *(const float4*)(up + 4);
    float4 t0 = make_float4(u0.x - acc[r][0], u0.y - acc[r][1], u0.z - acc[r][2], u0.w - acc[r][3]);
    float4 t1 = make_float4(u1.x - acc[r][4], u1.y - acc[r][5], u1.z - acc[r][6], u1.w - acc[r][7]);
    *(float4*)(tp) = t0;
    *(float4*)(tp + 4) = t1;
  }
}

// ---------------------------------------------------------------------------
// o = qg @ S_n + Aqk @ T  per chunk
// ---------------------------------------------------------------------------
__global__ __launch_bounds__(256) void oker(
    const float* __restrict__ qg, const float* __restrict__ Aqk,
    const float* __restrict__ Sst, const float* __restrict__ Tb, float* __restrict__ o) {
  __shared__ float Qs[BT_][HD_];
  __shared__ float As2[BT_][BT_];
  int bhn = blockIdx.x;
  int bh = bhn >> 5, n = bhn & 31;
  size_t base = ((size_t)bh * T_ + (size_t)n * BT_) * HD_;
  int tid = threadIdx.x;
#pragma unroll
  for (int s = 0; s < 8; ++s) {
    int fi = tid + s * 256;
    int row = fi >> 5;
    int col = (fi & 31) * 4;
    *(float4*)&Qs[row][col] = *(const float4*)(qg + base + (size_t)row * HD_ + col);
  }
  const float* Ap = Aqk + (size_t)bhn * BT_ * BT_;
#pragma unroll
  for (int s = 0; s < 16; ++s) {
    int e = tid + s * 256;
    ((float*)As2)[e] = Ap[e];
  }
  __syncthreads();
  const float* S = Sst + (size_t)bhn * HD_ * HD_;
  int i0 = (tid >> 4) * 4, vd0 = (tid & 15) * 8;
  float acc[4][8];
#pragma unroll
  for (int r = 0; r < 4; ++r)
#pragma unroll
    for (int c2 = 0; c2 < 8; ++c2) acc[r][c2] = 0.f;
  for (int kd = 0; kd < HD_; ++kd) {
    float sv[8];
    *(float4*)(sv)     = *(const float4*)(S + (size_t)kd * HD_ + vd0);
    *(float4*)(sv + 4) = *(const float4*)(S + (size_t)kd * HD_ + vd0 + 4);
#pragma unroll
    for (int r = 0; r < 4; ++r) {
      float qv = Qs[i0 + r][kd];
#pragma unroll
      for (int c2 = 0; c2 < 8; ++c2) acc[r][c2] = fmaf(qv, sv[c2], acc[r][c2]);
    }
  }
  for (int j = 0; j < BT_; ++j) {
    float tv[8];
    const float* tp = Tb + base + (size_t)j * HD_ + vd0;
    *(float4*)(tv)     = *(const float4*)(tp);
    *(float4*)(tv + 4) = *(const float4*)(tp + 4);
#pragma unroll
    for (int r = 0; r < 4; ++r) {
      float av = As2[i0 + r][j];
#pragma unroll
      for (int c2 = 0; c2 < 8; ++c2) acc[r][c2] = fmaf(av, tv[c2], acc[r][c2]);
    }
  }
#pragma unroll
  for (int r = 0; r < 4; ++r) {
    float* op = o + base + (size_t)(i0 + r) * HD_ + vd0;
    float4 v0 = make_float4(acc[r][0], acc[r][1], acc[r][2], acc[r][3]);
    float4 v1 = make_float4(acc[r][4], acc[r][5], acc[r][6], acc[r][7]);
    *(float4*)(op) = v0;
    *(float4*)(op + 4) = v1;
  }
}

// ---------------------------------------------------------------------------
// Epilogue: (B,H,T,HD)->(B,T,C), RMS-norm, *norm_w, *sigmoid(gate); bf16 out.
// ---------------------------------------------------------------------------
__global__ __launch_bounds__(128) void epi(
    const float* __restrict__ o, const __hip_bfloat16* __restrict__ gatef,
    const float* __restrict__ normw, __hip_bfloat16* __restrict__ o2) {
  int idx = blockIdx.x;
  int h = idx & 7;
  int t = (idx >> 3) & (T_ - 1);
  int b = idx >> 14;
  int d = threadIdx.x;
  float val = o[(((size_t)b * H_ + h) * T_ + t) * HD_ + d];
  float ss = val * val;
#pragma unroll
  for (int off = 32; off > 0; off >>= 1) ss += __shfl_down(ss, off);
  __shared__ float red[2];
  if ((d & 63) == 0) red[d >> 6] = ss;
  __syncthreads();
  float tot = red[0] + red[1];
  float ms = tot * (1.f / HD_);
  float r = rsqrtf(ms + EPS_RMS);
  float gv = __bfloat162float(gatef[(size_t)(b * T_ + t) * C_ + h * HD_ + d]);
  float sig = 1.f / (1.f + expf(-gv));
  o2[(size_t)(b * T_ + t) * C_ + h * HD_ + d] = __float2bfloat16(val * r * normw[d] * sig);
}

// ---------------------------------------------------------------------------
extern "C" void kernel_launch(void* const* d_in, const int* in_sizes, int n_in,
                              void* d_out, int out_size, void* d_ws, size_t ws_size,
                              hipStream_t stream) {
  (void)in_sizes; (void)n_in; (void)out_size;
  const float* x    = (const float*)d_in[0];
  const float* Wq   = (const float*)d_in[1];
  const float* Wk   = (const float*)d_in[2];
  const float* Wv   = (const float*)d_in[3];
  const float* cqw  = (const float*)d_in[4];
  const float* cqb  = (const float*)d_in[5];
  const float* ckw  = (const float*)d_in[6];
  const float* ckb  = (const float*)d_in[7];
  const float* cvw  = (const float*)d_in[8];
  const float* cvb  = (const float*)d_in[9];
  const float* Wad  = (const float*)d_in[10];
  const float* Wau  = (const float*)d_in[11];
  // d_in[12] = Wb : dead code in reference
  const float* Wgd  = (const float*)d_in[13];
  const float* Wgu  = (const float*)d_in[14];
  const float* normw= (const float*)d_in[15];
  const float* Wo   = (const float*)d_in[16];

  float* outp = (float*)d_out;                 // (B,T,D)
  float* Sout = outp + (size_t)M_ * D_;        // (B,H,HD,HD)

  const size_t SZ = (size_t)M_ * C_;           // 4,194,304 f32

  float* ws = (float*)d_ws;
  // f32-unit offsets (bf16 buffers annotated)
  __hip_bfloat16* pre_qkv = (__hip_bfloat16*)(ws);            // 1.5SZ (M x 3C bf16)
  float* a_full  = ws + 3 * SZ / 2;                            // SZ
  __hip_bfloat16* gatef = (__hip_bfloat16*)(ws + 5 * SZ / 2);  // 0.5SZ (M x C bf16)
  float* qg = ws + 3 * SZ;
  float* kp = ws + 4 * SZ;
  float* km = ws + 5 * SZ;
  float* vv = ws + 6 * SZ;
  float* gc = ws + 7 * SZ;
  float* w_ = ws + 8 * SZ;
  float* u  = ws + 9 * SZ;
  float* Ppre = ws + 10 * SZ;                                  // 2SZ
  __hip_bfloat16* xb = (__hip_bfloat16*)(ws + 12 * SZ);        // SZ (M x D bf16)
  __hip_bfloat16* Wt_qkv = (__hip_bfloat16*)(ws + 13 * SZ);    // 0.75SZ (3C x D bf16)
  size_t off = 13 * SZ + 3 * SZ / 4;
  __hip_bfloat16* Wt_dg = (__hip_bfloat16*)(ws + off); off += 262144;  // (256 x D)
  __hip_bfloat16* Wt_au = (__hip_bfloat16*)(ws + off); off += 65536;   // (C x HD)
  __hip_bfloat16* Wt_gu = (__hip_bfloat16*)(ws + off); off += 65536;   // (C x HD)
  __hip_bfloat16* Wt_o  = (__hip_bfloat16*)(ws + off); off += 1048576; // (D x C)
  __hip_bfloat16* ad_bf = (__hip_bfloat16*)(ws + off); off += 262144;  // (M x HD)
  __hip_bfloat16* gd_bf = (__hip_bfloat16*)(ws + off); off += 262144;  // (M x HD)
  size_t need = off * sizeof(float);
  if (ws_size < need) return;

  // aliases (disjoint lifetimes)
  float* slabs = Ppre;                              // 4 x (M x 256) f32, dead before ppre_k
  float* Akk = ws;                                  // 0.5SZ, after conv reads pre_qkv... (phase 4)
  float* Aqk = ws + SZ / 2;                         // 0.5SZ
  __hip_bfloat16* o2b = (__hip_bfloat16*)(ws + SZ); // 0.5SZ (M x C bf16), written by epi
  float* Tb = a_full;                               // a_full dead after gc_kernel
  float* ob = vv;                                   // vv dead after solvek

  // Phase 0: convert / transpose weights & activations to bf16
  cvt_bf<<<(int)((size_t)M_ * D_ / 1024), 256, 0, stream>>>(x, xb);
  tconv<<<dim3(C_ / 32, D_ / 32), 256, 0, stream>>>(Wq, Wt_qkv, D_, C_);
  tconv<<<dim3(C_ / 32, D_ / 32), 256, 0, stream>>>(Wk, Wt_qkv + (size_t)C_ * D_, D_, C_);
  tconv<<<dim3(C_ / 32, D_ / 32), 256, 0, stream>>>(Wv, Wt_qkv + 2 * (size_t)C_ * D_, D_, C_);
  tconv<<<dim3(HD_ / 32, D_ / 32), 256, 0, stream>>>(Wad, Wt_dg, D_, HD_);
  tconv<<<dim3(HD_ / 32, D_ / 32), 256, 0, stream>>>(Wgd, Wt_dg + (size_t)HD_ * D_, D_, HD_);
  tconv<<<dim3(C_ / 32, HD_ / 32), 256, 0, stream>>>(Wau, Wt_au, HD_, C_);
  tconv<<<dim3(C_ / 32, HD_ / 32), 256, 0, stream>>>(Wgu, Wt_gu, HD_, C_);
  tconv<<<dim3(D_ / 32, C_ / 32), 256, 0, stream>>>(Wo, Wt_o, C_, D_);

  // Phase 1: projections (MFMA bf16)
  gemm_bf16k<__hip_bfloat16><<<dim3(3 * C_ / 128, M_ / 128), 256, 0, stream>>>(
      xb, Wt_qkv, pre_qkv, 3 * C_, D_);
  gemm_bf16_sk<<<dim3(2, M_ / 128, 4), 256, 0, stream>>>(xb, Wt_dg, slabs, 256, D_, D_ / 4);
  reduce_dg<<<(int)((size_t)M_ * 256 / 256), 256, 0, stream>>>(slabs, ad_bf, gd_bf);
  gemm_bf16k<float><<<dim3(C_ / 128, M_ / 128), 256, 0, stream>>>(ad_bf, Wt_au, a_full, C_, HD_);
  gemm_bf16k<__hip_bfloat16><<<dim3(C_ / 128, M_ / 128), 256, 0, stream>>>(
      gd_bf, Wt_gu, gatef, C_, HD_);

  // Phase 2: conv + heads
  conv_norm_bf<<<B_ * T_ * H_, 128, 0, stream>>>(pre_qkv, cqw, cqb, qg);
  conv_norm_bf<<<B_ * T_ * H_, 128, 0, stream>>>(pre_qkv + C_, ckw, ckb, kp);
  conv_silu_bf<<<B_ * T_ * H_, 128, 0, stream>>>(pre_qkv + 2 * C_, cvw, cvb, vv);

  // Phase 3: decay cumsum + scaled q/k variants
  gc_kernel<<<B_ * H_ * NT_, 128, 0, stream>>>(a_full, gc);
  scale_qkk<<<(int)(SZ / 256), 256, 0, stream>>>(qg, kp, km, gc);

  // Phase 4: per-chunk matrices + triangular solve
  pairdot<<<dim3(B_ * H_ * NT_, 2), 256, 0, stream>>>(qg, kp, km, Akk, Aqk);
  solvek<<<dim3(B_ * H_ * NT_, 2), 128, 0, stream>>>(Akk, kp, vv, w_, u);

  // Phase 5: state scan
  ppre_k<<<B_ * H_ * NT_, 256, 0, stream>>>(km, u, Ppre);
  scan_k<<<B_ * H_ * HD_, 128, 0, stream>>>(Ppre, gc, Sout);

  // Phase 6: outputs
  tker<<<B_ * H_ * NT_, 256, 0, stream>>>(w_, u, Ppre, Tb);
  oker<<<B_ * H_ * NT_, 256, 0, stream>>>(qg, Aqk, Ppre, Tb, ob);
  epi<<<B_ * T_ * H_, 128, 0, stream>>>(ob, gatef, normw, o2b);
  gemm_bf16k<float><<<dim3(D_ / 128, M_ / 128), 256, 0, stream>>>(o2b, Wt_o, outp, D_, C_);
}